// Round 6
// baseline (104.287 us; speedup 1.0000x reference)
//
#include <hip/hip_runtime.h>
#include <math.h>

// Problem constants (match reference)
#define Bdim 8
#define Lq   256
#define Hd   128
#define NHd  4

static constexpr float kNEG = -4294967295.0f;           // -(2^32)+1 as f32
static constexpr float kScale = 0.17677669529663687f;   // 1/sqrt(32)

// async global->LDS DMA, 16B per lane. LDS dest = wave-uniform base + lane*16.
__device__ __forceinline__ void gld_lds16(const void* gptr, void* lptr) {
    __builtin_amdgcn_global_load_lds(
        (const __attribute__((address_space(1))) void*)gptr,
        (__attribute__((address_space(3))) void*)lptr, 16, 0, 0);
}
__device__ __forceinline__ void fence_sched() { __builtin_amdgcn_sched_barrier(0); }

// ---------------------------------------------------------------------------
// prep: blocks 0-11 transpose Wq/Wk/Wv (64x64 LDS tiles, coalesced both ways);
//       block 12 normalizes the bool time_mask (u8 vs i32 auto-detect).
// ---------------------------------------------------------------------------
__global__ __launch_bounds__(256) void prep_kernel(
    const float* __restrict__ Wq, const float* __restrict__ Wk,
    const float* __restrict__ Wv, const unsigned char* __restrict__ raw,
    float* __restrict__ Wt, int* __restrict__ outmask)
{
    const int blk = blockIdx.x;
    if (blk < 12) {
        __shared__ float tile[64][65];
        const int mi = blk >> 2;
        const float* W = (mi == 0) ? Wq : (mi == 1) ? Wk : Wv;
        float* WT = Wt + mi * (Hd * Hd);
        const int ti = blk & 3;
        const int r0 = (ti >> 1) * 64, c0 = (ti & 1) * 64;
        #pragma unroll
        for (int k = 0; k < 16; ++k) {
            const int e = threadIdx.x + k * 256;
            const int r = e >> 6, c = e & 63;
            tile[r][c] = W[(r0 + r) * Hd + (c0 + c)];
        }
        __syncthreads();
        #pragma unroll
        for (int k = 0; k < 16; ++k) {
            const int e = threadIdx.x + k * 256;
            const int r = e >> 6, c = e & 63;
            WT[(c0 + r) * Hd + (r0 + c)] = tile[c][r];
        }
    } else {
        __shared__ int cnt;
        if (threadIdx.x == 0) cnt = 0;
        __syncthreads();
        const int n = Bdim * Lq;
        for (int i = threadIdx.x; i < n; i += 256)
            if ((i & 3) && raw[i]) atomicAdd(&cnt, 1);
        __syncthreads();
        const bool is_u8 = (cnt > 0);
        const int* raw32 = (const int*)raw;
        for (int i = threadIdx.x; i < n; i += 256) {
            const int v = is_u8 ? (int)raw[i] : raw32[i];
            outmask[i] = (v != 0) ? 1 : 0;
        }
    }
}

// ---------------------------------------------------------------------------
// Projections (fused abs_pos adds), W pre-transposed so loads are coalesced.
// 512 threads (8 waves/block): o = tid&127, rh = tid>>7, 2 rows/thread.
// ---------------------------------------------------------------------------
__global__ __launch_bounds__(512) void proj_kernel(
    const float* __restrict__ queries, const float* __restrict__ keys,
    const float* __restrict__ absK, const float* __restrict__ absV,
    const float* __restrict__ Wt,
    const float* __restrict__ bq, const float* __restrict__ bk,
    const float* __restrict__ bv,
    float* __restrict__ Qb, float* __restrict__ Kb, float* __restrict__ Vb)
{
    constexpr int R = 8;
    __shared__ float xq[R][Hd];
    __shared__ float xk[R][Hd];
    const int row0 = blockIdx.x * R;
    const int tid = threadIdx.x;
    #pragma unroll
    for (int k = 0; k < 2; ++k) {
        const int e = tid + k * 512;
        const int r = e >> 7, c = e & 127;
        xq[r][c] = queries[(row0 + r) * Hd + c];
        xk[r][c] = keys[(row0 + r) * Hd + c];
    }
    __syncthreads();

    const int o = tid & 127, rh = tid >> 7;
    const int r0 = rh * 2, r1 = rh * 2 + 1;
    const float* __restrict__ Wtq = Wt;
    const float* __restrict__ Wtk = Wt + Hd * Hd;
    const float* __restrict__ Wtv = Wt + 2 * Hd * Hd;

    float qa0 = bq[o], qa1 = qa0;
    float ka0 = bk[o] + absK[(row0 + r0) * Hd + o];
    float ka1 = bk[o] + absK[(row0 + r1) * Hd + o];
    float va0 = bv[o] + absV[(row0 + r0) * Hd + o];
    float va1 = bv[o] + absV[(row0 + r1) * Hd + o];

    #pragma unroll 4
    for (int i = 0; i < Hd; ++i) {
        const float wq = Wtq[i * Hd + o];
        const float wk = Wtk[i * Hd + o];
        const float wv = Wtv[i * Hd + o];
        const float x0 = xq[r0][i], x1 = xq[r1][i];
        const float y0 = xk[r0][i], y1 = xk[r1][i];
        qa0 += x0 * wq; qa1 += x1 * wq;
        ka0 += y0 * wk; ka1 += y1 * wk;
        va0 += y0 * wv; va1 += y1 * wv;
    }
    Qb[(row0 + r0) * Hd + o] = qa0;  Qb[(row0 + r1) * Hd + o] = qa1;
    Kb[(row0 + r0) * Hd + o] = ka0;  Kb[(row0 + r1) * Hd + o] = ka1;
    Vb[(row0 + r0) * Hd + o] = va0;  Vb[(row0 + r1) * Hd + o] = va1;
}

// ---------------------------------------------------------------------------
// Fused attention, one block per (b,l), 256 threads = 4 waves; wave w owns
// head w. XCD-pinned: blockIdx = l_disp*8 + b, so bid%8 = b -> batch b's
// blocks share one XCD and its L2 holds that batch's K/V slabs (2 MB < 4 MB).
// Double-buffered LDS staging (T3/T4): issue tile t+1, s_waitcnt vmcnt(4)
// (never 0 mid-loop), raw s_barrier, compute tile t, lgkmcnt(0), s_barrier.
// XOR swizzle (16B unit ^ (row&7)) on BOTH global source and LDS read.
// Masked rows: uniform 1/256 fast path. l bit-reversed for balance.
// ---------------------------------------------------------------------------
__global__ __launch_bounds__(256) void attn_kernel(
    const float* __restrict__ Qb, const float* __restrict__ Kb,
    const float* __restrict__ Vb,
    const float* __restrict__ tK, const float* __restrict__ tV,
    const int* __restrict__ tmask, float* __restrict__ out)
{
    const int bid = blockIdx.x;
    const int b = bid & 7;                      // XCD pin: bid%8 -> XCD b
    int ld = bid >> 3;                          // bit-reverse 8 bits
    ld = ((ld & 0x55) << 1) | ((ld >> 1) & 0x55);
    ld = ((ld & 0x33) << 2) | ((ld >> 2) & 0x33);
    ld = ((ld & 0x0F) << 4) | ((ld >> 4) & 0x0F);
    const int l = ld;
    const int tid = threadIdx.x;
    const int w = tid >> 6;                     // wave = head
    const int lane = tid & 63;
    const int c8 = (w << 2) | (tid & 3);        // 8-float channel group
    const int m_off = (tid >> 2) & 15;

    __shared__ float sc[NHd][Lq];               // 4 KB scores
    __shared__ float bufK[2][2048];             // 2 x 8 KB: K / V tiles
    __shared__ float bufT[2][2048];             // 2 x 8 KB: tK / tV tiles

    const size_t rowbase = ((size_t)b * Lq + l) * Hd;
    float4 q0 = *(const float4*)(Qb + rowbase + c8 * 8);
    float4 q1 = *(const float4*)(Qb + rowbase + c8 * 8 + 4);
    q0.x *= kScale; q0.y *= kScale; q0.z *= kScale; q0.w *= kScale;
    q1.x *= kScale; q1.y *= kScale; q1.z *= kScale; q1.w *= kScale;

    const char* Kslab = (const char*)(Kb + (size_t)b * Lq * Hd);
    const char* Vslab = (const char*)(Vb + (size_t)b * Lq * Hd);
    const char* tKrow = (const char*)(tK + rowbase * Lq);
    const char* tVrow = (const char*)(tV + rowbase * Lq);

    // staging: tile = 512 16B-units; this thread's slots + swizzled global src
    const int s0 = w * 128 + lane;
    const int g0 = (s0 ^ ((s0 >> 5) & 7)) * 16;
    const int g1 = ((s0 + 64) ^ (((s0 + 64) >> 5) & 7)) * 16;
    const int ldsoff = w * 2048;                // bytes within one buffer set

    // swizzled read slots: unit (m_off, c8*2+j) ^ (m_off&7)
    const int su0 = ((m_off * 32 + c8 * 2)     ^ (m_off & 7)) * 16;
    const int su1 = ((m_off * 32 + c8 * 2 + 1) ^ (m_off & 7)) * 16;

    const bool rowmask = (tmask[b * Lq + l] != 0);
    const int nt = (l >> 4) + 1;                // tiles of 16 m-rows

    if (!rowmask) {
        // ---- phase 1: scores sc[w][m] = Qs.(Keff[m]+tK[l,m]) ----
        {   // prologue
            char* dK = (char*)bufK[0] + ldsoff;
            char* dT = (char*)bufT[0] + ldsoff;
            gld_lds16(Kslab + g0, dK);  gld_lds16(Kslab + g1, dK + 1024);
            gld_lds16(tKrow + g0, dT);  gld_lds16(tKrow + g1, dT + 1024);
        }
        for (int t = 0; t < nt; ++t) {
            if (t + 1 < nt) {
                const size_t tb = (size_t)(t + 1) * 8192;
                char* dK = (char*)bufK[(t + 1) & 1] + ldsoff;
                char* dT = (char*)bufT[(t + 1) & 1] + ldsoff;
                gld_lds16(Kslab + tb + g0, dK);
                gld_lds16(Kslab + tb + g1, dK + 1024);
                gld_lds16(tKrow + tb + g0, dT);
                gld_lds16(tKrow + tb + g1, dT + 1024);
                fence_sched();
                asm volatile("s_waitcnt vmcnt(4)" ::: "memory");
            } else {
                asm volatile("s_waitcnt vmcnt(0)" ::: "memory");
            }
            fence_sched();
            __builtin_amdgcn_s_barrier();       // tile t fully in LDS
            fence_sched();
            const int set = t & 1;
            const float4 k0 = *(const float4*)((const char*)bufK[set] + su0);
            const float4 k1 = *(const float4*)((const char*)bufK[set] + su1);
            const float4 t0 = *(const float4*)((const char*)bufT[set] + su0);
            const float4 t1 = *(const float4*)((const char*)bufT[set] + su1);
            float p = q0.x * (k0.x + t0.x) + q0.y * (k0.y + t0.y)
                    + q0.z * (k0.z + t0.z) + q0.w * (k0.w + t0.w)
                    + q1.x * (k1.x + t1.x) + q1.y * (k1.y + t1.y)
                    + q1.z * (k1.z + t1.z) + q1.w * (k1.w + t1.w);
            p += __shfl_xor(p, 1);
            p += __shfl_xor(p, 2);
            const int m = t * 16 + m_off;
            if ((tid & 3) == 0) sc[w][m] = (m <= l) ? p : kNEG;
            fence_sched();
            asm volatile("s_waitcnt lgkmcnt(0)" ::: "memory");
            __builtin_amdgcn_s_barrier();       // reads done before overwrite
            fence_sched();
        }

        // ---- softmax, wave-local on own head; every tile read guarded ----
        {
            float v0s = (lane       <= l) ? sc[w][lane]       : kNEG;
            float v1s = (lane + 64  <= l) ? sc[w][lane + 64]  : kNEG;
            float v2s = (lane + 128 <= l) ? sc[w][lane + 128] : kNEG;
            float v3s = (lane + 192 <= l) ? sc[w][lane + 192] : kNEG;
            float mx = fmaxf(fmaxf(v0s, v1s), fmaxf(v2s, v3s));
            #pragma unroll
            for (int d = 1; d < 64; d <<= 1) mx = fmaxf(mx, __shfl_xor(mx, d));
            v0s = expf(v0s - mx); v1s = expf(v1s - mx);
            v2s = expf(v2s - mx); v3s = expf(v3s - mx);
            float ssum = v0s + v1s + v2s + v3s;
            #pragma unroll
            for (int d = 1; d < 64; d <<= 1) ssum += __shfl_xor(ssum, d);
            const float inv = 1.0f / ssum;
            // writeback covers ALL 256 entries; m>l become exact 0
            sc[w][lane]       = v0s * inv;
            sc[w][lane + 64]  = v1s * inv;
            sc[w][lane + 128] = v2s * inv;
            sc[w][lane + 192] = v3s * inv;
        }
        // no barrier: sc[w] produced and consumed by wave w only
    }

    // ---- phase 2: out[c] = sum_m A[m] * (Veff[m,c] + tV[l,m,c]) ----
    const int nto = rowmask ? (Lq / 16) : nt;
    float4 acc0 = {0.f, 0.f, 0.f, 0.f}, acc1 = {0.f, 0.f, 0.f, 0.f};
    {   // prologue
        char* dK = (char*)bufK[0] + ldsoff;
        char* dT = (char*)bufT[0] + ldsoff;
        gld_lds16(Vslab + g0, dK);  gld_lds16(Vslab + g1, dK + 1024);
        gld_lds16(tVrow + g0, dT);  gld_lds16(tVrow + g1, dT + 1024);
    }
    for (int t = 0; t < nto; ++t) {
        if (t + 1 < nto) {
            const size_t tb = (size_t)(t + 1) * 8192;
            char* dK = (char*)bufK[(t + 1) & 1] + ldsoff;
            char* dT = (char*)bufT[(t + 1) & 1] + ldsoff;
            gld_lds16(Vslab + tb + g0, dK);
            gld_lds16(Vslab + tb + g1, dK + 1024);
            gld_lds16(tVrow + tb + g0, dT);
            gld_lds16(tVrow + tb + g1, dT + 1024);
            fence_sched();
            asm volatile("s_waitcnt vmcnt(4)" ::: "memory");
        } else {
            asm volatile("s_waitcnt vmcnt(0)" ::: "memory");
        }
        fence_sched();
        __builtin_amdgcn_s_barrier();
        fence_sched();
        const int set = t & 1;
        const float aw = rowmask ? 0.00390625f : sc[w][t * 16 + m_off];
        const float4 v0 = *(const float4*)((const char*)bufK[set] + su0);
        const float4 v1 = *(const float4*)((const char*)bufK[set] + su1);
        const float4 t0 = *(const float4*)((const char*)bufT[set] + su0);
        const float4 t1 = *(const float4*)((const char*)bufT[set] + su1);
        acc0.x += aw * (v0.x + t0.x); acc0.y += aw * (v0.y + t0.y);
        acc0.z += aw * (v0.z + t0.z); acc0.w += aw * (v0.w + t0.w);
        acc1.x += aw * (v1.x + t1.x); acc1.y += aw * (v1.y + t1.y);
        acc1.z += aw * (v1.z + t1.z); acc1.w += aw * (v1.w + t1.w);
        fence_sched();
        asm volatile("s_waitcnt lgkmcnt(0)" ::: "memory");
        __builtin_amdgcn_s_barrier();
        fence_sched();
    }
    // reduce across the 16 m_off lane-groups (bits 2..5 of lane)
    #pragma unroll
    for (int d = 4; d < 64; d <<= 1) {
        acc0.x += __shfl_xor(acc0.x, d); acc0.y += __shfl_xor(acc0.y, d);
        acc0.z += __shfl_xor(acc0.z, d); acc0.w += __shfl_xor(acc0.w, d);
        acc1.x += __shfl_xor(acc1.x, d); acc1.y += __shfl_xor(acc1.y, d);
        acc1.z += __shfl_xor(acc1.z, d); acc1.w += __shfl_xor(acc1.w, d);
    }
    if (m_off == 0) {
        *(float4*)(out + rowbase + c8 * 8)     = acc0;
        *(float4*)(out + rowbase + c8 * 8 + 4) = acc1;
    }
}

// ---------------------------------------------------------------------------
extern "C" void kernel_launch(void* const* d_in, const int* in_sizes, int n_in,
                              void* d_out, int out_size, void* d_ws, size_t ws_size,
                              hipStream_t stream) {
    const float* queries = (const float*)d_in[0];
    const float* keys    = (const float*)d_in[1];
    const float* tK      = (const float*)d_in[2];
    const float* tV      = (const float*)d_in[3];
    const float* absK    = (const float*)d_in[4];
    const float* absV    = (const float*)d_in[5];
    const float* Wq      = (const float*)d_in[6];
    const float* bq      = (const float*)d_in[7];
    const float* Wk      = (const float*)d_in[8];
    const float* bk      = (const float*)d_in[9];
    const float* Wv      = (const float*)d_in[10];
    const float* bv      = (const float*)d_in[11];
    const unsigned char* tmask_raw = (const unsigned char*)d_in[12];
    // d_in[13] (attn_mask) is deterministic triu(k=1) -> handled in-kernel.

    float* outp = (float*)d_out;

    const int rows = Bdim * Lq;                    // 2048
    float* Qb = (float*)d_ws;                      // 1 MB
    float* Kb = Qb + (size_t)rows * Hd;            // 1 MB
    float* Vb = Kb + (size_t)rows * Hd;            // 1 MB
    int* tmask = (int*)(Vb + (size_t)rows * Hd);   // 8 KB
    float* Wt = (float*)(tmask + rows);            // 192 KB (3 transposed W)

    prep_kernel<<<13, 256, 0, stream>>>(Wq, Wk, Wv, tmask_raw, Wt, tmask);
    proj_kernel<<<rows / 8, 512, 0, stream>>>(queries, keys, absK, absV, Wt,
                                              bq, bk, bv, Qb, Kb, Vb);
    attn_kernel<<<rows, 256, 0, stream>>>(Qb, Kb, Vb, tK, tV, tmask, outp);
}

// Round 7
// 92.937 us; speedup vs baseline: 1.1221x; 1.1221x over previous
//
#include <hip/hip_runtime.h>
#include <math.h>

// Problem constants (match reference)
#define Bdim 8
#define Lq   256
#define Hd   128

static constexpr float kNEG = -4294967295.0f;           // -(2^32)+1 as f32
static constexpr float kScale = 0.17677669529663687f;   // 1/sqrt(32)
static constexpr float kUni = 0.00390625f;              // 1/256 (exact)

// ---------------------------------------------------------------------------
// prep: blocks 0-11 transpose Wq/Wk/Wv (64x64 LDS tiles, coalesced both ways);
//       block 12 normalizes the bool time_mask (u8 vs i32 auto-detect).
// ---------------------------------------------------------------------------
__global__ __launch_bounds__(256) void prep_kernel(
    const float* __restrict__ Wq, const float* __restrict__ Wk,
    const float* __restrict__ Wv, const unsigned char* __restrict__ raw,
    float* __restrict__ Wt, int* __restrict__ outmask)
{
    const int blk = blockIdx.x;
    if (blk < 12) {
        __shared__ float tile[64][65];
        const int mi = blk >> 2;
        const float* W = (mi == 0) ? Wq : (mi == 1) ? Wk : Wv;
        float* WT = Wt + mi * (Hd * Hd);
        const int ti = blk & 3;
        const int r0 = (ti >> 1) * 64, c0 = (ti & 1) * 64;
        #pragma unroll
        for (int k = 0; k < 16; ++k) {
            const int e = threadIdx.x + k * 256;
            const int r = e >> 6, c = e & 63;
            tile[r][c] = W[(r0 + r) * Hd + (c0 + c)];
        }
        __syncthreads();
        #pragma unroll
        for (int k = 0; k < 16; ++k) {
            const int e = threadIdx.x + k * 256;
            const int r = e >> 6, c = e & 63;
            WT[(c0 + r) * Hd + (r0 + c)] = tile[c][r];
        }
    } else {
        __shared__ int cnt;
        if (threadIdx.x == 0) cnt = 0;
        __syncthreads();
        const int n = Bdim * Lq;
        for (int i = threadIdx.x; i < n; i += 256)
            if ((i & 3) && raw[i]) atomicAdd(&cnt, 1);
        __syncthreads();
        const bool is_u8 = (cnt > 0);
        const int* raw32 = (const int*)raw;
        for (int i = threadIdx.x; i < n; i += 256) {
            const int v = is_u8 ? (int)raw[i] : raw32[i];
            outmask[i] = (v != 0) ? 1 : 0;
        }
    }
}

// ---------------------------------------------------------------------------
// Projections (fused abs_pos adds), W pre-transposed so loads are coalesced.
// 512 threads (8 waves/block): o = tid&127, rh = tid>>7, 2 rows/thread.
// ---------------------------------------------------------------------------
__global__ __launch_bounds__(512) void proj_kernel(
    const float* __restrict__ queries, const float* __restrict__ keys,
    const float* __restrict__ absK, const float* __restrict__ absV,
    const float* __restrict__ Wt,
    const float* __restrict__ bq, const float* __restrict__ bk,
    const float* __restrict__ bv,
    float* __restrict__ Qb, float* __restrict__ Kb, float* __restrict__ Vb)
{
    constexpr int R = 8;
    __shared__ float xq[R][Hd];
    __shared__ float xk[R][Hd];
    const int row0 = blockIdx.x * R;
    const int tid = threadIdx.x;
    #pragma unroll
    for (int k = 0; k < 2; ++k) {
        const int e = tid + k * 512;
        const int r = e >> 7, c = e & 127;
        xq[r][c] = queries[(row0 + r) * Hd + c];
        xk[r][c] = keys[(row0 + r) * Hd + c];
    }
    __syncthreads();

    const int o = tid & 127, rh = tid >> 7;
    const int r0 = rh * 2, r1 = rh * 2 + 1;
    const float* __restrict__ Wtq = Wt;
    const float* __restrict__ Wtk = Wt + Hd * Hd;
    const float* __restrict__ Wtv = Wt + 2 * Hd * Hd;

    float qa0 = bq[o], qa1 = qa0;
    float ka0 = bk[o] + absK[(row0 + r0) * Hd + o];
    float ka1 = bk[o] + absK[(row0 + r1) * Hd + o];
    float va0 = bv[o] + absV[(row0 + r0) * Hd + o];
    float va1 = bv[o] + absV[(row0 + r1) * Hd + o];

    #pragma unroll 4
    for (int i = 0; i < Hd; ++i) {
        const float wq = Wtq[i * Hd + o];
        const float wk = Wtk[i * Hd + o];
        const float wv = Wtv[i * Hd + o];
        const float x0 = xq[r0][i], x1 = xq[r1][i];
        const float y0 = xk[r0][i], y1 = xk[r1][i];
        qa0 += x0 * wq; qa1 += x1 * wq;
        ka0 += y0 * wk; ka1 += y1 * wk;
        va0 += y0 * wv; va1 += y1 * wv;
    }
    Qb[(row0 + r0) * Hd + o] = qa0;  Qb[(row0 + r1) * Hd + o] = qa1;
    Kb[(row0 + r0) * Hd + o] = ka0;  Kb[(row0 + r1) * Hd + o] = ka1;
    Vb[(row0 + r0) * Hd + o] = va0;  Vb[(row0 + r1) * Hd + o] = va1;
}

// ---------------------------------------------------------------------------
// Fused attention v4: 1024 blocks = (b:8) x (hp:2) x (lgroup:64). 4 waves per
// block, each wave fully independent: wave w -> head hp*2+(w&1), l-rows
// {4i+2(w>>1), +1}. K/V tiles loaded to REGISTERS once per tile and reused
// across the wave's 2 l's (halves the K/V L3->L2 re-read traffic). Scores and
// softmax weights live entirely in registers (static 16-tile unroll; rule #20
// satisfied); softmax = register + shuffle. ZERO LDS, ZERO barriers.
// Lane map: m_off=(tid>>2)&15 (m within tile), cg=tid&3 (8-ch group of head).
// Masked rows: exact uniform 1/256 weights over all 256 m.
// l-groups bit-reversed across the grid for load balance.
// ---------------------------------------------------------------------------
__global__ __launch_bounds__(256) void attn_kernel(
    const float* __restrict__ Qb, const float* __restrict__ Kb,
    const float* __restrict__ Vb,
    const float* __restrict__ tK, const float* __restrict__ tV,
    const int* __restrict__ tmask, float* __restrict__ out)
{
    const int bid = blockIdx.x;
    const int b  = bid & 7;                 // XCD pin (harmless, keeps L2 tidy)
    const int hp = (bid >> 3) & 1;
    const int id = bid >> 4;                // 0..63
    const int i  = ((id & 1) << 5) | ((id & 2) << 3) | ((id & 4) << 1)
                 | ((id & 8) >> 1) | ((id & 16) >> 3) | ((id & 32) >> 5);

    const int tid = threadIdx.x;
    const int w = tid >> 6;
    const int h = hp * 2 + (w & 1);
    const int l0 = i * 4 + (w >> 1) * 2;
    const int l1 = l0 + 1;
    const int m_off = (tid >> 2) & 15;
    const int cg = tid & 3;
    const int ch = h * 32 + cg * 8;

    // Q rows (pre-scaled by 1/sqrt(D))
    const float* q0b = Qb + ((size_t)b * Lq + l0) * Hd + ch;
    const float* q1b = Qb + ((size_t)b * Lq + l1) * Hd + ch;
    float4 q00 = ((const float4*)q0b)[0], q01 = ((const float4*)q0b)[1];
    float4 q10 = ((const float4*)q1b)[0], q11 = ((const float4*)q1b)[1];
    q00.x*=kScale; q00.y*=kScale; q00.z*=kScale; q00.w*=kScale;
    q01.x*=kScale; q01.y*=kScale; q01.z*=kScale; q01.w*=kScale;
    q10.x*=kScale; q10.y*=kScale; q10.z*=kScale; q10.w*=kScale;
    q11.x*=kScale; q11.y*=kScale; q11.z*=kScale; q11.w*=kScale;

    const bool mk0 = (tmask[b * Lq + l0] != 0);
    const bool mk1 = (tmask[b * Lq + l1] != 0);
    const int ntc0 = (l0 >> 4) + 1, ntc1 = (l1 >> 4) + 1;   // causal tiles
    const int n10 = mk0 ? 0 : ntc0, n11 = mk1 ? 0 : ntc1;   // phase-1 bounds
    const int NT1 = (n10 > n11) ? n10 : n11;
    const int n20 = mk0 ? 16 : ntc0, n21 = mk1 ? 16 : ntc1; // phase-2 bounds
    const int NT2 = (n20 > n21) ? n20 : n21;

    const float* kpt = Kb + (size_t)b * Lq * Hd + m_off * Hd + ch;
    const float* vpt = Vb + (size_t)b * Lq * Hd + m_off * Hd + ch;
    const float* t0p = tK + (((size_t)b * Lq + l0) * Lq + m_off) * Hd + ch;
    const float* t1p = tK + (((size_t)b * Lq + l1) * Lq + m_off) * Hd + ch;
    const float* u0p = tV + (((size_t)b * Lq + l0) * Lq + m_off) * Hd + ch;
    const float* u1p = tV + (((size_t)b * Lq + l1) * Lq + m_off) * Hd + ch;

    // ---- phase 1: scores in registers (K-tile regs shared by both l's) ----
    float s0[16], s1[16];
    #pragma unroll
    for (int t = 0; t < 16; ++t) { s0[t] = kNEG; s1[t] = kNEG; }

    #pragma unroll
    for (int t = 0; t < 16; ++t) {
        if (t < NT1) {
            const float4 ka = *(const float4*)(kpt + t * 2048);
            const float4 kb = *(const float4*)(kpt + t * 2048 + 4);
            const int m = t * 16 + m_off;
            if (t < n10) {
                const float4 ta = *(const float4*)(t0p + t * 2048);
                const float4 tb = *(const float4*)(t0p + t * 2048 + 4);
                float p = q00.x*(ka.x+ta.x) + q00.y*(ka.y+ta.y)
                        + q00.z*(ka.z+ta.z) + q00.w*(ka.w+ta.w)
                        + q01.x*(kb.x+tb.x) + q01.y*(kb.y+tb.y)
                        + q01.z*(kb.z+tb.z) + q01.w*(kb.w+tb.w);
                p += __shfl_xor(p, 1);
                p += __shfl_xor(p, 2);
                s0[t] = (m <= l0) ? p : kNEG;
            }
            if (t < n11) {
                const float4 ta = *(const float4*)(t1p + t * 2048);
                const float4 tb = *(const float4*)(t1p + t * 2048 + 4);
                float p = q10.x*(ka.x+ta.x) + q10.y*(ka.y+ta.y)
                        + q10.z*(ka.z+ta.z) + q10.w*(ka.w+ta.w)
                        + q11.x*(kb.x+tb.x) + q11.y*(kb.y+tb.y)
                        + q11.z*(kb.z+tb.z) + q11.w*(kb.w+tb.w);
                p += __shfl_xor(p, 1);
                p += __shfl_xor(p, 2);
                s1[t] = (m <= l1) ? p : kNEG;
            }
        }
    }

    // ---- softmax, fully in registers (reduce over m_off = lane bits 2..5) --
    if (!mk0) {
        float mx = s0[0];
        #pragma unroll
        for (int t = 1; t < 16; ++t) mx = fmaxf(mx, s0[t]);
        #pragma unroll
        for (int d = 4; d < 64; d <<= 1) mx = fmaxf(mx, __shfl_xor(mx, d));
        float sum = 0.f;
        #pragma unroll
        for (int t = 0; t < 16; ++t) { s0[t] = expf(s0[t] - mx); sum += s0[t]; }
        #pragma unroll
        for (int d = 4; d < 64; d <<= 1) sum += __shfl_xor(sum, d);
        const float inv = 1.0f / sum;
        #pragma unroll
        for (int t = 0; t < 16; ++t) s0[t] *= inv;
    } else {
        #pragma unroll
        for (int t = 0; t < 16; ++t) s0[t] = kUni;
    }
    if (!mk1) {
        float mx = s1[0];
        #pragma unroll
        for (int t = 1; t < 16; ++t) mx = fmaxf(mx, s1[t]);
        #pragma unroll
        for (int d = 4; d < 64; d <<= 1) mx = fmaxf(mx, __shfl_xor(mx, d));
        float sum = 0.f;
        #pragma unroll
        for (int t = 0; t < 16; ++t) { s1[t] = expf(s1[t] - mx); sum += s1[t]; }
        #pragma unroll
        for (int d = 4; d < 64; d <<= 1) sum += __shfl_xor(sum, d);
        const float inv = 1.0f / sum;
        #pragma unroll
        for (int t = 0; t < 16; ++t) s1[t] *= inv;
    } else {
        #pragma unroll
        for (int t = 0; t < 16; ++t) s1[t] = kUni;
    }

    // ---- phase 2: output (V-tile regs shared by both l's; weights are
    //      already lane-aligned with V rows -> no shuffles in the loop) ----
    float4 a00 = {0,0,0,0}, a01 = {0,0,0,0};
    float4 a10 = {0,0,0,0}, a11 = {0,0,0,0};
    #pragma unroll
    for (int t = 0; t < 16; ++t) {
        if (t < NT2) {
            const float4 va = *(const float4*)(vpt + t * 2048);
            const float4 vb = *(const float4*)(vpt + t * 2048 + 4);
            if (t < n20) {
                const float4 ta = *(const float4*)(u0p + t * 2048);
                const float4 tb = *(const float4*)(u0p + t * 2048 + 4);
                const float aw = s0[t];
                a00.x += aw*(va.x+ta.x); a00.y += aw*(va.y+ta.y);
                a00.z += aw*(va.z+ta.z); a00.w += aw*(va.w+ta.w);
                a01.x += aw*(vb.x+tb.x); a01.y += aw*(vb.y+tb.y);
                a01.z += aw*(vb.z+tb.z); a01.w += aw*(vb.w+tb.w);
            }
            if (t < n21) {
                const float4 ta = *(const float4*)(u1p + t * 2048);
                const float4 tb = *(const float4*)(u1p + t * 2048 + 4);
                const float aw = s1[t];
                a10.x += aw*(va.x+ta.x); a10.y += aw*(va.y+ta.y);
                a10.z += aw*(va.z+ta.z); a10.w += aw*(va.w+ta.w);
                a11.x += aw*(vb.x+tb.x); a11.y += aw*(vb.y+tb.y);
                a11.z += aw*(vb.z+tb.z); a11.w += aw*(vb.w+tb.w);
            }
        }
    }
    // reduce over the 16 m_off lane-groups
    #pragma unroll
    for (int d = 4; d < 64; d <<= 1) {
        a00.x += __shfl_xor(a00.x, d); a00.y += __shfl_xor(a00.y, d);
        a00.z += __shfl_xor(a00.z, d); a00.w += __shfl_xor(a00.w, d);
        a01.x += __shfl_xor(a01.x, d); a01.y += __shfl_xor(a01.y, d);
        a01.z += __shfl_xor(a01.z, d); a01.w += __shfl_xor(a01.w, d);
        a10.x += __shfl_xor(a10.x, d); a10.y += __shfl_xor(a10.y, d);
        a10.z += __shfl_xor(a10.z, d); a10.w += __shfl_xor(a10.w, d);
        a11.x += __shfl_xor(a11.x, d); a11.y += __shfl_xor(a11.y, d);
        a11.z += __shfl_xor(a11.z, d); a11.w += __shfl_xor(a11.w, d);
    }
    if (m_off == 0) {
        float* o0 = out + ((size_t)b * Lq + l0) * Hd + ch;
        ((float4*)o0)[0] = a00; ((float4*)o0)[1] = a01;
        float* o1 = out + ((size_t)b * Lq + l1) * Hd + ch;
        ((float4*)o1)[0] = a10; ((float4*)o1)[1] = a11;
    }
}

// ---------------------------------------------------------------------------
extern "C" void kernel_launch(void* const* d_in, const int* in_sizes, int n_in,
                              void* d_out, int out_size, void* d_ws, size_t ws_size,
                              hipStream_t stream) {
    const float* queries = (const float*)d_in[0];
    const float* keys    = (const float*)d_in[1];
    const float* tK      = (const float*)d_in[2];
    const float* tV      = (const float*)d_in[3];
    const float* absK    = (const float*)d_in[4];
    const float* absV    = (const float*)d_in[5];
    const float* Wq      = (const float*)d_in[6];
    const float* bq      = (const float*)d_in[7];
    const float* Wk      = (const float*)d_in[8];
    const float* bk      = (const float*)d_in[9];
    const float* Wv      = (const float*)d_in[10];
    const float* bv      = (const float*)d_in[11];
    const unsigned char* tmask_raw = (const unsigned char*)d_in[12];
    // d_in[13] (attn_mask) is deterministic triu(k=1) -> handled in-kernel.

    float* outp = (float*)d_out;

    const int rows = Bdim * Lq;                    // 2048
    float* Qb = (float*)d_ws;                      // 1 MB
    float* Kb = Qb + (size_t)rows * Hd;            // 1 MB
    float* Vb = Kb + (size_t)rows * Hd;            // 1 MB
    int* tmask = (int*)(Vb + (size_t)rows * Hd);   // 8 KB
    float* Wt = (float*)(tmask + rows);            // 192 KB (3 transposed W)

    prep_kernel<<<13, 256, 0, stream>>>(Wq, Wk, Wv, tmask_raw, Wt, tmask);
    proj_kernel<<<rows / 8, 512, 0, stream>>>(queries, keys, absK, absV, Wt,
                                              bq, bk, bv, Qb, Kb, Vb);
    attn_kernel<<<1024, 256, 0, stream>>>(Qb, Kb, Vb, tK, tV, tmask, outp);
}

// Round 8
// 77.156 us; speedup vs baseline: 1.3516x; 1.2045x over previous
//
#include <hip/hip_runtime.h>
#include <math.h>

// Problem constants (match reference)
#define Bdim 8
#define Lq   256
#define Hd   128

static constexpr float kNEG = -4294967295.0f;           // -(2^32)+1 as f32
static constexpr float kScale = 0.17677669529663687f;   // 1/sqrt(32)
static constexpr float kUni = 0.00390625f;              // 1/256 (exact)

// ---------------------------------------------------------------------------
// prep: blocks 0-11 transpose Wq/Wk/Wv (64x64 LDS tiles, coalesced both ways);
//       block 12 normalizes the bool time_mask (u8 vs i32 auto-detect).
// ---------------------------------------------------------------------------
__global__ __launch_bounds__(256) void prep_kernel(
    const float* __restrict__ Wq, const float* __restrict__ Wk,
    const float* __restrict__ Wv, const unsigned char* __restrict__ raw,
    float* __restrict__ Wt, int* __restrict__ outmask)
{
    const int blk = blockIdx.x;
    if (blk < 12) {
        __shared__ float tile[64][65];
        const int mi = blk >> 2;
        const float* W = (mi == 0) ? Wq : (mi == 1) ? Wk : Wv;
        float* WT = Wt + mi * (Hd * Hd);
        const int ti = blk & 3;
        const int r0 = (ti >> 1) * 64, c0 = (ti & 1) * 64;
        #pragma unroll
        for (int k = 0; k < 16; ++k) {
            const int e = threadIdx.x + k * 256;
            const int r = e >> 6, c = e & 63;
            tile[r][c] = W[(r0 + r) * Hd + (c0 + c)];
        }
        __syncthreads();
        #pragma unroll
        for (int k = 0; k < 16; ++k) {
            const int e = threadIdx.x + k * 256;
            const int r = e >> 6, c = e & 63;
            WT[(c0 + r) * Hd + (r0 + c)] = tile[c][r];
        }
    } else {
        __shared__ int cnt;
        if (threadIdx.x == 0) cnt = 0;
        __syncthreads();
        const int n = Bdim * Lq;
        for (int i = threadIdx.x; i < n; i += 256)
            if ((i & 3) && raw[i]) atomicAdd(&cnt, 1);
        __syncthreads();
        const bool is_u8 = (cnt > 0);
        const int* raw32 = (const int*)raw;
        for (int i = threadIdx.x; i < n; i += 256) {
            const int v = is_u8 ? (int)raw[i] : raw32[i];
            outmask[i] = (v != 0) ? 1 : 0;
        }
    }
}

// ---------------------------------------------------------------------------
// Projections (fused abs_pos adds), W pre-transposed so loads are coalesced.
// 512 threads (8 waves/block): o = tid&127, rh = tid>>7, 2 rows/thread.
// ---------------------------------------------------------------------------
__global__ __launch_bounds__(512) void proj_kernel(
    const float* __restrict__ queries, const float* __restrict__ keys,
    const float* __restrict__ absK, const float* __restrict__ absV,
    const float* __restrict__ Wt,
    const float* __restrict__ bq, const float* __restrict__ bk,
    const float* __restrict__ bv,
    float* __restrict__ Qb, float* __restrict__ Kb, float* __restrict__ Vb)
{
    constexpr int R = 8;
    __shared__ float xq[R][Hd];
    __shared__ float xk[R][Hd];
    const int row0 = blockIdx.x * R;
    const int tid = threadIdx.x;
    #pragma unroll
    for (int k = 0; k < 2; ++k) {
        const int e = tid + k * 512;
        const int r = e >> 7, c = e & 127;
        xq[r][c] = queries[(row0 + r) * Hd + c];
        xk[r][c] = keys[(row0 + r) * Hd + c];
    }
    __syncthreads();

    const int o = tid & 127, rh = tid >> 7;
    const int r0 = rh * 2, r1 = rh * 2 + 1;
    const float* __restrict__ Wtq = Wt;
    const float* __restrict__ Wtk = Wt + Hd * Hd;
    const float* __restrict__ Wtv = Wt + 2 * Hd * Hd;

    float qa0 = bq[o], qa1 = qa0;
    float ka0 = bk[o] + absK[(row0 + r0) * Hd + o];
    float ka1 = bk[o] + absK[(row0 + r1) * Hd + o];
    float va0 = bv[o] + absV[(row0 + r0) * Hd + o];
    float va1 = bv[o] + absV[(row0 + r1) * Hd + o];

    #pragma unroll 4
    for (int i = 0; i < Hd; ++i) {
        const float wq = Wtq[i * Hd + o];
        const float wk = Wtk[i * Hd + o];
        const float wv = Wtv[i * Hd + o];
        const float x0 = xq[r0][i], x1 = xq[r1][i];
        const float y0 = xk[r0][i], y1 = xk[r1][i];
        qa0 += x0 * wq; qa1 += x1 * wq;
        ka0 += y0 * wk; ka1 += y1 * wk;
        va0 += y0 * wv; va1 += y1 * wv;
    }
    Qb[(row0 + r0) * Hd + o] = qa0;  Qb[(row0 + r1) * Hd + o] = qa1;
    Kb[(row0 + r0) * Hd + o] = ka0;  Kb[(row0 + r1) * Hd + o] = ka1;
    Vb[(row0 + r0) * Hd + o] = va0;  Vb[(row0 + r1) * Hd + o] = va1;
}

// ---------------------------------------------------------------------------
// Fused attention v5: 1024 blocks = (b:8) x (hp:2) x (j:64). 4 waves/block,
// each wave independent: wave w -> head hp*2+(w&1), COMPLEMENTARY l-pair
// p = j*2+(w>>1), l0 = p, l1 = 255-p. Per-wave work = (p+1)+(256-p) = 257
// rows = CONSTANT -> perfect load balance on every CU regardless of the
// (undefined) block->CU dispatch policy. (Rounds 4-7 all had per-CU l
// correlation under stride-256 round-robin -> ~1.8x makespan inflation.)
// K/V tiles loaded to registers once per tile, reused across both l's.
// Scores+softmax fully in registers (static 16-tile unroll); zero LDS,
// zero barriers. Masked rows: exact uniform 1/256 path.
// Lane map: m_off=(tid>>2)&15 (m within tile), cg=tid&3 (8-ch group of head).
// ---------------------------------------------------------------------------
__global__ __launch_bounds__(256) void attn_kernel(
    const float* __restrict__ Qb, const float* __restrict__ Kb,
    const float* __restrict__ Vb,
    const float* __restrict__ tK, const float* __restrict__ tV,
    const int* __restrict__ tmask, float* __restrict__ out)
{
    const int bid = blockIdx.x;
    const int b  = bid & 7;
    const int hp = (bid >> 3) & 1;
    const int j  = bid >> 4;                // 0..63

    const int tid = threadIdx.x;
    const int w = tid >> 6;
    const int h = hp * 2 + (w & 1);
    const int p = j * 2 + (w >> 1);         // 0..127
    const int l0 = p;
    const int l1 = 255 - p;
    const int m_off = (tid >> 2) & 15;
    const int cg = tid & 3;
    const int ch = h * 32 + cg * 8;

    // Q rows (pre-scaled by 1/sqrt(D))
    const float* q0b = Qb + ((size_t)b * Lq + l0) * Hd + ch;
    const float* q1b = Qb + ((size_t)b * Lq + l1) * Hd + ch;
    float4 q00 = ((const float4*)q0b)[0], q01 = ((const float4*)q0b)[1];
    float4 q10 = ((const float4*)q1b)[0], q11 = ((const float4*)q1b)[1];
    q00.x*=kScale; q00.y*=kScale; q00.z*=kScale; q00.w*=kScale;
    q01.x*=kScale; q01.y*=kScale; q01.z*=kScale; q01.w*=kScale;
    q10.x*=kScale; q10.y*=kScale; q10.z*=kScale; q10.w*=kScale;
    q11.x*=kScale; q11.y*=kScale; q11.z*=kScale; q11.w*=kScale;

    const bool mk0 = (tmask[b * Lq + l0] != 0);
    const bool mk1 = (tmask[b * Lq + l1] != 0);
    const int ntc0 = (l0 >> 4) + 1, ntc1 = (l1 >> 4) + 1;   // causal tiles
    const int n10 = mk0 ? 0 : ntc0, n11 = mk1 ? 0 : ntc1;   // phase-1 bounds
    const int NT1 = (n10 > n11) ? n10 : n11;
    const int n20 = mk0 ? 16 : ntc0, n21 = mk1 ? 16 : ntc1; // phase-2 bounds
    const int NT2 = (n20 > n21) ? n20 : n21;

    const float* kpt = Kb + (size_t)b * Lq * Hd + m_off * Hd + ch;
    const float* vpt = Vb + (size_t)b * Lq * Hd + m_off * Hd + ch;
    const float* t0p = tK + (((size_t)b * Lq + l0) * Lq + m_off) * Hd + ch;
    const float* t1p = tK + (((size_t)b * Lq + l1) * Lq + m_off) * Hd + ch;
    const float* u0p = tV + (((size_t)b * Lq + l0) * Lq + m_off) * Hd + ch;
    const float* u1p = tV + (((size_t)b * Lq + l1) * Lq + m_off) * Hd + ch;

    // ---- phase 1: scores in registers (K-tile regs shared by both l's) ----
    float s0[16], s1[16];
    #pragma unroll
    for (int t = 0; t < 16; ++t) { s0[t] = kNEG; s1[t] = kNEG; }

    #pragma unroll
    for (int t = 0; t < 16; ++t) {
        if (t < NT1) {
            const float4 ka = *(const float4*)(kpt + t * 2048);
            const float4 kb = *(const float4*)(kpt + t * 2048 + 4);
            const int m = t * 16 + m_off;
            if (t < n10) {
                const float4 ta = *(const float4*)(t0p + t * 2048);
                const float4 tb = *(const float4*)(t0p + t * 2048 + 4);
                float pp = q00.x*(ka.x+ta.x) + q00.y*(ka.y+ta.y)
                         + q00.z*(ka.z+ta.z) + q00.w*(ka.w+ta.w)
                         + q01.x*(kb.x+tb.x) + q01.y*(kb.y+tb.y)
                         + q01.z*(kb.z+tb.z) + q01.w*(kb.w+tb.w);
                pp += __shfl_xor(pp, 1);
                pp += __shfl_xor(pp, 2);
                s0[t] = (m <= l0) ? pp : kNEG;
            }
            if (t < n11) {
                const float4 ta = *(const float4*)(t1p + t * 2048);
                const float4 tb = *(const float4*)(t1p + t * 2048 + 4);
                float pp = q10.x*(ka.x+ta.x) + q10.y*(ka.y+ta.y)
                         + q10.z*(ka.z+ta.z) + q10.w*(ka.w+ta.w)
                         + q11.x*(kb.x+tb.x) + q11.y*(kb.y+tb.y)
                         + q11.z*(kb.z+tb.z) + q11.w*(kb.w+tb.w);
                pp += __shfl_xor(pp, 1);
                pp += __shfl_xor(pp, 2);
                s1[t] = (m <= l1) ? pp : kNEG;
            }
        }
    }

    // ---- softmax, fully in registers (reduce over m_off = lane bits 2..5) --
    if (!mk0) {
        float mx = s0[0];
        #pragma unroll
        for (int t = 1; t < 16; ++t) mx = fmaxf(mx, s0[t]);
        #pragma unroll
        for (int d = 4; d < 64; d <<= 1) mx = fmaxf(mx, __shfl_xor(mx, d));
        float sum = 0.f;
        #pragma unroll
        for (int t = 0; t < 16; ++t) { s0[t] = expf(s0[t] - mx); sum += s0[t]; }
        #pragma unroll
        for (int d = 4; d < 64; d <<= 1) sum += __shfl_xor(sum, d);
        const float inv = 1.0f / sum;
        #pragma unroll
        for (int t = 0; t < 16; ++t) s0[t] *= inv;
    } else {
        #pragma unroll
        for (int t = 0; t < 16; ++t) s0[t] = kUni;
    }
    if (!mk1) {
        float mx = s1[0];
        #pragma unroll
        for (int t = 1; t < 16; ++t) mx = fmaxf(mx, s1[t]);
        #pragma unroll
        for (int d = 4; d < 64; d <<= 1) mx = fmaxf(mx, __shfl_xor(mx, d));
        float sum = 0.f;
        #pragma unroll
        for (int t = 0; t < 16; ++t) { s1[t] = expf(s1[t] - mx); sum += s1[t]; }
        #pragma unroll
        for (int d = 4; d < 64; d <<= 1) sum += __shfl_xor(sum, d);
        const float inv = 1.0f / sum;
        #pragma unroll
        for (int t = 0; t < 16; ++t) s1[t] *= inv;
    } else {
        #pragma unroll
        for (int t = 0; t < 16; ++t) s1[t] = kUni;
    }

    // ---- phase 2: output (V-tile regs shared by both l's; weights are
    //      already lane-aligned with V rows -> no shuffles in the loop) ----
    float4 a00 = {0,0,0,0}, a01 = {0,0,0,0};
    float4 a10 = {0,0,0,0}, a11 = {0,0,0,0};
    #pragma unroll
    for (int t = 0; t < 16; ++t) {
        if (t < NT2) {
            const float4 va = *(const float4*)(vpt + t * 2048);
            const float4 vb = *(const float4*)(vpt + t * 2048 + 4);
            if (t < n20) {
                const float4 ta = *(const float4*)(u0p + t * 2048);
                const float4 tb = *(const float4*)(u0p + t * 2048 + 4);
                const float aw = s0[t];
                a00.x += aw*(va.x+ta.x); a00.y += aw*(va.y+ta.y);
                a00.z += aw*(va.z+ta.z); a00.w += aw*(va.w+ta.w);
                a01.x += aw*(vb.x+tb.x); a01.y += aw*(vb.y+tb.y);
                a01.z += aw*(vb.z+tb.z); a01.w += aw*(vb.w+tb.w);
            }
            if (t < n21) {
                const float4 ta = *(const float4*)(u1p + t * 2048);
                const float4 tb = *(const float4*)(u1p + t * 2048 + 4);
                const float aw = s1[t];
                a10.x += aw*(va.x+ta.x); a10.y += aw*(va.y+ta.y);
                a10.z += aw*(va.z+ta.z); a10.w += aw*(va.w+ta.w);
                a11.x += aw*(vb.x+tb.x); a11.y += aw*(vb.y+tb.y);
                a11.z += aw*(vb.z+tb.z); a11.w += aw*(vb.w+tb.w);
            }
        }
    }
    // reduce over the 16 m_off lane-groups
    #pragma unroll
    for (int d = 4; d < 64; d <<= 1) {
        a00.x += __shfl_xor(a00.x, d); a00.y += __shfl_xor(a00.y, d);
        a00.z += __shfl_xor(a00.z, d); a00.w += __shfl_xor(a00.w, d);
        a01.x += __shfl_xor(a01.x, d); a01.y += __shfl_xor(a01.y, d);
        a01.z += __shfl_xor(a01.z, d); a01.w += __shfl_xor(a01.w, d);
        a10.x += __shfl_xor(a10.x, d); a10.y += __shfl_xor(a10.y, d);
        a10.z += __shfl_xor(a10.z, d); a10.w += __shfl_xor(a10.w, d);
        a11.x += __shfl_xor(a11.x, d); a11.y += __shfl_xor(a11.y, d);
        a11.z += __shfl_xor(a11.z, d); a11.w += __shfl_xor(a11.w, d);
    }
    if (m_off == 0) {
        float* o0 = out + ((size_t)b * Lq + l0) * Hd + ch;
        ((float4*)o0)[0] = a00; ((float4*)o0)[1] = a01;
        float* o1 = out + ((size_t)b * Lq + l1) * Hd + ch;
        ((float4*)o1)[0] = a10; ((float4*)o1)[1] = a11;
    }
}

// ---------------------------------------------------------------------------
extern "C" void kernel_launch(void* const* d_in, const int* in_sizes, int n_in,
                              void* d_out, int out_size, void* d_ws, size_t ws_size,
                              hipStream_t stream) {
    const float* queries = (const float*)d_in[0];
    const float* keys    = (const float*)d_in[1];
    const float* tK      = (const float*)d_in[2];
    const float* tV      = (const float*)d_in[3];
    const float* absK    = (const float*)d_in[4];
    const float* absV    = (const float*)d_in[5];
    const float* Wq      = (const float*)d_in[6];
    const float* bq      = (const float*)d_in[7];
    const float* Wk      = (const float*)d_in[8];
    const float* bk      = (const float*)d_in[9];
    const float* Wv      = (const float*)d_in[10];
    const float* bv      = (const float*)d_in[11];
    const unsigned char* tmask_raw = (const unsigned char*)d_in[12];
    // d_in[13] (attn_mask) is deterministic triu(k=1) -> handled in-kernel.

    float* outp = (float*)d_out;

    const int rows = Bdim * Lq;                    // 2048
    float* Qb = (float*)d_ws;                      // 1 MB
    float* Kb = Qb + (size_t)rows * Hd;            // 1 MB
    float* Vb = Kb + (size_t)rows * Hd;            // 1 MB
    int* tmask = (int*)(Vb + (size_t)rows * Hd);   // 8 KB
    float* Wt = (float*)(tmask + rows);            // 192 KB (3 transposed W)

    prep_kernel<<<13, 256, 0, stream>>>(Wq, Wk, Wv, tmask_raw, Wt, tmask);
    proj_kernel<<<rows / 8, 512, 0, stream>>>(queries, keys, absK, absV, Wt,
                                              bq, bk, bv, Qb, Kb, Vb);
    attn_kernel<<<1024, 256, 0, stream>>>(Qb, Kb, Vb, tK, tV, tmask, outp);
}